// Round 9
// baseline (142.015 us; speedup 1.0000x reference)
//
#include <hip/hip_runtime.h>

#define B_ 4
#define T_ 4096
#define C_ 1024
#define H_ 64

typedef _Float16 half8  __attribute__((ext_vector_type(8)));
typedef _Float16 half4_ __attribute__((ext_vector_type(4)));
typedef float    floatx4 __attribute__((ext_vector_type(4)));

#define MFMA16(a, b, c)  __builtin_amdgcn_mfma_f32_16x16x32_f16(a, b, c, 0, 0, 0)
#define MFMA16K(a, b, c) __builtin_amdgcn_mfma_f32_16x16x16f16(a, b, c, 0, 0, 0)
#define LO4(v) __builtin_shufflevector(v, v, 0, 1, 2, 3)
#define HI4(v) __builtin_shufflevector(v, v, 4, 5, 6, 7)

// ---------------------------------------------------------------------------
// Kernel 1: pack W into MFMA-fragment order (lane-contiguous A-frags).
// ---------------------------------------------------------------------------
__global__ __launch_bounds__(256) void pack_w_kn(
    const float* __restrict__ Wq, const float* __restrict__ Wk,
    const float* __restrict__ Wv, _Float16* __restrict__ Wt2)
{
    const int idx  = blockIdx.x * 256 + threadIdx.x;  // 0 .. 196607
    const int mt   = idx >> 14;
    const int j    = (idx >> 10) & 15;
    const int f    = (idx >> 9) & 1;
    const int lane = (idx >> 3) & 63;
    const int jj   = idx & 7;
    const int q = lane >> 4, c = lane & 15;
    const int k  = j * 64 + f * 32 + q * 8 + jj;
    const int hp = mt * 16 + c;                       // 0..191
    const float* W = (hp < 64) ? Wq : (hp < 128) ? Wk : Wv;
    Wt2[idx] = (_Float16)W[k * H_ + (hp & 63)];
}

// ---------------------------------------------------------------------------
// Kernel 2: fused QKV projection (unchanged).  Vpk in 16x16x16 A-frag order.
// ---------------------------------------------------------------------------
__global__ __launch_bounds__(512) void qkv_kn(
    const float* __restrict__ x, const _Float16* __restrict__ Wt2,
    _Float16* __restrict__ Qh, _Float16* __restrict__ Kpk,
    _Float16* __restrict__ Vpk)
{
    __shared__ _Float16 xs[2][32][72];                // 9216 B
    const int tid  = threadIdx.x;
    const int lane = tid & 63, w = tid >> 6;
    const int q    = lane >> 4, c = lane & 15;
    const int nt   = w & 1;                           // n-half (16 rows)
    const int mg   = w >> 1;                          // m-group (3 m-tiles)
    const int row0 = blockIdx.x * 32;

    const int srow = tid >> 4, scol = (tid & 15) * 4;
    const float* xg = x + (size_t)(row0 + srow) * C_ + scol;

    floatx4 acc[3];
    #pragma unroll
    for (int i = 0; i < 3; ++i) acc[i] = floatx4{0.f, 0.f, 0.f, 0.f};

    float4 g = *(const float4*)xg;                    // preload tile 0

    for (int j = 0; j < 16; ++j) {
        half4_ hv;
        hv[0] = (_Float16)g.x; hv[1] = (_Float16)g.y;
        hv[2] = (_Float16)g.z; hv[3] = (_Float16)g.w;
        *(half4_*)(&xs[j & 1][srow][scol]) = hv;
        __syncthreads();
        if (j < 15) g = *(const float4*)(xg + (j + 1) * 64);

        const _Float16* xrow = &xs[j & 1][nt * 16 + c][q * 8];
        const half8 b0 = *(const half8*)xrow;
        const half8 b1 = *(const half8*)(xrow + 32);

        half8 a[6];
        #pragma unroll
        for (int i = 0; i < 3; ++i) {
            const size_t fb = ((size_t)((mg * 3 + i) * 16 + j) * 2) * 512 + lane * 8;
            a[i * 2]     = *(const half8*)(Wt2 + fb);
            a[i * 2 + 1] = *(const half8*)(Wt2 + fb + 512);
        }
        #pragma unroll
        for (int i = 0; i < 3; ++i) {
            acc[i] = MFMA16(a[i * 2],     b0, acc[i]);
            acc[i] = MFMA16(a[i * 2 + 1], b1, acc[i]);
        }
    }

    const int row = row0 + nt * 16 + c;
    const int b = row >> 12, t4 = row & (T_ - 1);
    const int kt = t4 >> 6;
    const size_t tbase = ((size_t)b * 64 + kt) * 4096;
    const int mtk = (t4 >> 4) & 3;
    const int kk  = t4 & 63;

    #pragma unroll
    for (int i = 0; i < 3; ++i) {
        const int gi = mg * 3 + i;
        if (gi < 4) {                                 // Q row-major
            half4_ v;
            #pragma unroll
            for (int r = 0; r < 4; ++r) v[r] = (_Float16)acc[i][r];
            *(half4_*)(Qh + (size_t)row * H_ + gi * 16 + q * 4) = v;
        } else if (gi < 8) {                          // K fragment-packed (16x16x32 A-frag)
            half4_ v;
            #pragma unroll
            for (int r = 0; r < 4; ++r) v[r] = (_Float16)acc[i][r];
            const int e  = gi - 4;
            const int f  = e >> 1;
            const int qa = (e * 2 + (q >> 1)) & 3;
            *(half4_*)(Kpk + tbase + ((size_t)(mtk * 2 + f) * 64 + qa * 16 + c) * 8
                       + (q & 1) * 4) = v;
        } else {                                      // V 16x16x16 A-frag packed
            const int mtv = gi - 8;
            const int qa2 = (kk >> 2) & 3;
            const int h4  = (kk >> 4) & 1;
            const int f2  = kk >> 5;
            const int i2  = kk & 3;
            #pragma unroll
            for (int r = 0; r < 4; ++r) {
                const int cv = q * 4 + r;             // h & 15
                Vpk[tbase + ((size_t)(mtv * 2 + f2) * 64 + qa2 * 16 + cv) * 8
                    + h4 * 4 + i2] = (_Float16)acc[i][r];
            }
        }
    }
}

// ---------------------------------------------------------------------------
// Kernel 3: causal flash attention, LDS-SHARED K/V (the round-8 post-mortem
// fix: per-wave private K/V loads made 8 waves each pull the full 16 KB tile
// from L2 -> 532 MB stream ~= the 33-40 us wall since round 1).
// Block = 128 q-rows (8 waves x 16 rows, softmax state wave-private), 8-way
// split-K ACROSS blocks (kt == s mod 8), K/V staged once per block into
// double-buffered LDS (32 KB): traffic 532 -> 67.6 MB.  2 barriers/tile,
// next-tile loads issued before compute (latency hides under QK+softmax+PV).
// Per-wave unnormalized partials (o, m, l) -> combine_kn merges 8 per q-row.
// ---------------------------------------------------------------------------
__global__ __launch_bounds__(512, 4) void attn_kn(
    const _Float16* __restrict__ Qh, const _Float16* __restrict__ Kpk,
    const _Float16* __restrict__ Vpk, float* __restrict__ Opart,
    float* __restrict__ Mp, float* __restrict__ Lp)
{
    __shared__ __align__(16) _Float16 KVs[2][2][4096]; // 32 KB, dbuf x {K,V}
    const int tid  = threadIdx.x;
    const int lane = tid & 63;
    const int w    = tid >> 6;                        // 0..7
    const int q    = lane >> 4, c = lane & 15;

    // decode: batch per XCD pair; tau heavy-first; s = split-K slice
    const int bid  = blockIdx.x;
    const int xcd  = bid & 7;
    const int slot = bid >> 3;                        // 0..127
    const int b    = xcd >> 1;
    const int tau  = 31 - (slot >> 2);                // 0..31, heavy first
    const int s    = ((slot & 3) << 1) | (xcd & 1);   // 0..7
    const int row0 = tau * 128;
    const int wrow0 = row0 + w * 16;                  // this wave's first row
    const int nk_blk = 2 * tau + 2;                   // block stages kt<nk_blk
    const int nk_w   = (wrow0 >> 6) + 1;              // wave needs kt<nk_w
    const int ntb = (s < nk_blk) ? (((nk_blk - 1 - s) >> 3) + 1) : 0;

    // Q B-frag for this wave's 16 rows, pre-scaled by (1/8)*log2(e)
    const _Float16* qb = Qh + (size_t)(b * T_ + wrow0 + c) * H_;
    half8 bq0 = *(const half8*)(qb + q * 8);
    half8 bq1 = *(const half8*)(qb + 32 + q * 8);
    const _Float16 qs = (_Float16)0.18033688f;
    bq0 *= qs; bq1 *= qs;

    floatx4 o[4];
    #pragma unroll
    for (int i = 0; i < 4; ++i) o[i] = floatx4{0.f, 0.f, 0.f, 0.f};
    float m = -3.0e38f, l = 0.f;

    const _Float16* Kb = Kpk + (size_t)b * 262144;    // b * 64 * 4096
    const _Float16* Vb = Vpk + (size_t)b * 262144;

    if (ntb > 0) {                                    // stage first tile
        const _Float16* Kt = Kb + (size_t)s * 4096;
        const _Float16* Vt = Vb + (size_t)s * 4096;
        *(half8*)(&KVs[0][0][tid * 8]) = *(const half8*)(Kt + tid * 8);
        *(half8*)(&KVs[0][1][tid * 8]) = *(const half8*)(Vt + tid * 8);
    }
    __syncthreads();

    #pragma unroll 1
    for (int i = 0; i < ntb; ++i) {
        const int kt = s + 8 * i;
        const bool more = (i + 1 < ntb);
        half8 gk, gv;
        if (more) {                                   // issue next-tile loads
            const _Float16* Kt = Kb + (size_t)(kt + 8) * 4096;
            const _Float16* Vt = Vb + (size_t)(kt + 8) * 4096;
            gk = *(const half8*)(Kt + tid * 8);
            gv = *(const half8*)(Vt + tid * 8);
        }

        if (kt < nk_w) {                              // wave-uniform guard
            const _Float16* Ks = &KVs[i & 1][0][0];
            const _Float16* Vs = &KVs[i & 1][1][0];

            floatx4 sS[4];
            __builtin_amdgcn_s_setprio(1);
            #pragma unroll
            for (int mt = 0; mt < 4; ++mt) {
                const half8 ka = *(const half8*)(Ks + ((mt * 2)     * 64 + lane) * 8);
                const half8 kb2= *(const half8*)(Ks + ((mt * 2 + 1) * 64 + lane) * 8);
                floatx4 z = floatx4{0.f, 0.f, 0.f, 0.f};
                z = MFMA16(ka, bq0, z);
                sS[mt] = MFMA16(kb2, bq1, z);
            }
            __builtin_amdgcn_s_setprio(0);

            if (kt == nk_w - 1) {                     // causal mask (diag tile)
                const int kb0 = kt * 64;
                #pragma unroll
                for (int mt = 0; mt < 4; ++mt)
                    #pragma unroll
                    for (int r = 0; r < 4; ++r)
                        if (kb0 + mt * 16 + q * 4 + r > wrow0 + c)
                            sS[mt][r] = -3.0e38f;
            }

            // online softmax (lane holds 16 scores of ONE q-row); T13 defer
            float mx = sS[0][0];
            #pragma unroll
            for (int mt = 0; mt < 4; ++mt)
                #pragma unroll
                for (int r = 0; r < 4; ++r) mx = fmaxf(mx, sS[mt][r]);
            mx = fmaxf(mx, __shfl_xor(mx, 16, 64));
            mx = fmaxf(mx, __shfl_xor(mx, 32, 64));
            if (!__all(mx <= m + 8.f)) {
                const float mn    = fmaxf(m, mx);
                const float alpha = exp2f(m - mn);
                l *= alpha;
                #pragma unroll
                for (int mt = 0; mt < 4; ++mt) o[mt] *= alpha;
                m = mn;
            }
            half4_ ph[4];
            float sl = 0.f;
            #pragma unroll
            for (int mt = 0; mt < 4; ++mt)
                #pragma unroll
                for (int r = 0; r < 4; ++r) {
                    const float ev = exp2f(sS[mt][r] - m);
                    sl += ev;
                    ph[mt][r] = (_Float16)ev;
                }
            sl += __shfl_xor(sl, 16, 64);
            sl += __shfl_xor(sl, 32, 64);
            l += sl;

            __builtin_amdgcn_s_setprio(1);
            #pragma unroll
            for (int mt = 0; mt < 4; ++mt) {
                const half8 va = *(const half8*)(Vs + ((mt * 2)     * 64 + lane) * 8);
                const half8 vb = *(const half8*)(Vs + ((mt * 2 + 1) * 64 + lane) * 8);
                o[mt] = MFMA16K(LO4(va), ph[0], o[mt]);
                o[mt] = MFMA16K(HI4(va), ph[1], o[mt]);
                o[mt] = MFMA16K(LO4(vb), ph[2], o[mt]);
                o[mt] = MFMA16K(HI4(vb), ph[3], o[mt]);
            }
            __builtin_amdgcn_s_setprio(0);
        }

        __syncthreads();                              // all reads of buf done
        if (more) {                                   // block-uniform
            *(half8*)(&KVs[(i + 1) & 1][0][tid * 8]) = gk;
            *(half8*)(&KVs[(i + 1) & 1][1][tid * 8]) = gv;
            __syncthreads();
        }
    }

    // ---- write per-wave unnormalized partial (fragment-native, coalesced) -
    float* Ob = Opart + ((size_t)bid * 8 + w) * 1024;
    #pragma unroll
    for (int mt = 0; mt < 4; ++mt)
        *(floatx4*)(Ob + mt * 256 + lane * 4) = o[mt];
    if (q == 0) {
        Mp[(size_t)bid * 128 + w * 16 + c] = m;
        Lp[(size_t)bid * 128 + w * 16 + c] = l;
    }
}

// ---------------------------------------------------------------------------
// Kernel 4: merge the 8 split-K partials per q-row, normalize, transpose via
// LDS, write out.  Grid 1024 blocks (b, tau, w) x 64 threads (one wave).
// ---------------------------------------------------------------------------
__global__ __launch_bounds__(64) void combine_kn(
    const float* __restrict__ Opart, const float* __restrict__ Mp,
    const float* __restrict__ Lp, float* __restrict__ out)
{
    __shared__ float sO[64][17];
    const int cb  = blockIdx.x;
    const int w2  = cb & 7;
    const int tau = (cb >> 3) & 31;
    const int b   = cb >> 8;
    const int lane = threadIdx.x;
    const int q = lane >> 4, c = lane & 15;

    int items[8];
    #pragma unroll
    for (int s = 0; s < 8; ++s) {
        const int xcd  = b * 2 + (s & 1);
        const int slot = (31 - tau) * 4 + (s >> 1);
        items[s] = slot * 8 + xcd;
    }

    float Mv[8], Lv[8];
    #pragma unroll
    for (int s = 0; s < 8; ++s) {
        Mv[s] = Mp[(size_t)items[s] * 128 + w2 * 16 + c];
        Lv[s] = Lp[(size_t)items[s] * 128 + w2 * 16 + c];
    }
    float M = Mv[0];
    #pragma unroll
    for (int s = 1; s < 8; ++s) M = fmaxf(M, Mv[s]);
    float L = 0.f;
    float a[8];
    #pragma unroll
    for (int s = 0; s < 8; ++s) {
        a[s] = exp2f(Mv[s] - M);                      // 0 for empty partials
        L += Lv[s] * a[s];
    }
    const float inv = 1.f / L;

    floatx4 acc[4];
    #pragma unroll
    for (int mt = 0; mt < 4; ++mt) acc[mt] = floatx4{0.f, 0.f, 0.f, 0.f};
    #pragma unroll
    for (int s = 0; s < 8; ++s) {
        const float* Ob = Opart + ((size_t)items[s] * 8 + w2) * 1024;
        #pragma unroll
        for (int mt = 0; mt < 4; ++mt) {
            const floatx4 v = *(const floatx4*)(Ob + mt * 256 + lane * 4);
            acc[mt] += v * a[s];
        }
    }
    #pragma unroll
    for (int mt = 0; mt < 4; ++mt)
        #pragma unroll
        for (int r = 0; r < 4; ++r)
            sO[mt * 16 + q * 4 + r][c] = acc[mt][r] * inv;
    __syncthreads();

    const int orow = lane >> 2;                       // 0..15
    const int seg  = lane & 3;                        // h segment of 16
    float* dst = out + (size_t)(b * T_ + tau * 128 + w2 * 16 + orow) * H_ + seg * 16;
    #pragma unroll
    for (int v4 = 0; v4 < 4; ++v4) {
        float4 vv;
        vv.x = sO[seg * 16 + v4 * 4 + 0][orow];
        vv.y = sO[seg * 16 + v4 * 4 + 1][orow];
        vv.z = sO[seg * 16 + v4 * 4 + 2][orow];
        vv.w = sO[seg * 16 + v4 * 4 + 3][orow];
        *(float4*)(dst + v4 * 4) = vv;
    }
}

extern "C" void kernel_launch(void* const* d_in, const int* in_sizes, int n_in,
                              void* d_out, int out_size, void* d_ws, size_t ws_size,
                              hipStream_t stream) {
    const float* x  = (const float*)d_in[0];
    const float* Wq = (const float*)d_in[1];
    const float* Wk = (const float*)d_in[2];
    const float* Wv = (const float*)d_in[3];
    float* out = (float*)d_out;

    _Float16* ws = (_Float16*)d_ws;
    _Float16* Wt2 = ws;                               //   192*1024 = 196608 halfs
    _Float16* Qh  = ws + 196608;                      // 16384*64  = 1048576
    _Float16* Kpk = Qh + 1048576;                     // [4][64][4096]
    _Float16* Vpk = Kpk + 1048576;                    // [4][64][4096]
    float* Opart = (float*)(ws + 3342336);            // [1024][8][1024] f32 = 32 MB
    float* Mp    = Opart + 8388608;                   // [1024][128]
    float* Lp    = Mp + 131072;                       // [1024][128]

    hipLaunchKernelGGL(pack_w_kn, dim3(768), dim3(256), 0, stream, Wq, Wk, Wv, Wt2);
    hipLaunchKernelGGL(qkv_kn, dim3((B_ * T_) / 32), dim3(512), 0, stream,
                       x, Wt2, Qh, Kpk, Vpk);
    hipLaunchKernelGGL(attn_kn, dim3(1024), dim3(512), 0, stream,
                       Qh, Kpk, Vpk, Opart, Mp, Lp);
    hipLaunchKernelGGL(combine_kn, dim3(1024), dim3(64), 0, stream,
                       Opart, Mp, Lp, out);
}